// Round 9
// baseline (50.505 us; speedup 1.0000x reference)
//
#include <hip/hip_runtime.h>
#include <hip/hip_bf16.h>

// Problem constants: B=32768, D=768, C=200.
#define NROWS 32768
#define DIMS  768
#define NC    200
#define CPAD  256
#define KSTEP 32
#define NSTEP (DIMS / KSTEP)   // 24
#define ROWSB 32               // M-tile rows per block -> grid 1024 = 4 blocks/CU

typedef __attribute__((ext_vector_type(8))) short short8;   // 8 bf16
typedef __attribute__((ext_vector_type(4))) float f32x4;

__device__ __forceinline__ unsigned pk_bf16(float lo, float hi) {
  union { __hip_bfloat162 h; unsigned u; } c;
  c.h = __float22bfloat162_rn(make_float2(lo, hi));
  return c.u;
}

// Kernel 1: L2-normalize centers -> bf16, K-blocked layout:
// (c,d) -> cnb2[(d>>5)*CPAD*KSTEP + c*KSTEP + (d&31)]; rows >= NC zero.
// Also zeroes the output scalar.
__global__ __launch_bounds__(256) void prep_centers_k(const float* __restrict__ centers,
                                                      short* __restrict__ cnb2,
                                                      float* __restrict__ out) {
  const int c = blockIdx.x;
  const int tid = threadIdx.x;
  if (c == 0 && tid == 0) out[0] = 0.f;
  if (c >= NC) {
    for (int d = tid; d < DIMS; d += 256)
      cnb2[(d >> 5) * (CPAD * KSTEP) + c * KSTEP + (d & 31)] = 0;
    return;
  }
  float ssq = 0.f;
  for (int d = tid; d < DIMS; d += 256) {
    float v = centers[c * DIMS + d];
    ssq += v * v;
  }
#pragma unroll
  for (int off = 32; off > 0; off >>= 1) ssq += __shfl_down(ssq, off);
  __shared__ float red[4];
  const int wid = tid >> 6, lane = tid & 63;
  if (lane == 0) red[wid] = ssq;
  __syncthreads();
  const float tot = red[0] + red[1] + red[2] + red[3];
  const float inv = 1.f / fmaxf(sqrtf(tot), 1e-8f);
  for (int d = tid; d < DIMS; d += 256) {
    const float v = centers[c * DIMS + d] * inv;
    union { __hip_bfloat16 h; short s; } cv;
    cv.h = __float2bfloat16(v);
    cnb2[(d >> 5) * (CPAD * KSTEP) + c * KSTEP + (d & 31)] = cv.s;
  }
}

// Kernel 2: dbuf LDS GEMM (round-6 structure) at 4 blocks/CU.
// Block = 4 waves = 32 rows x 256 cols, BK=32. Wave w owns cols w*64..
// (wave tile 32x64, acc[2][4]). Per step: prefetch(s+1) -> compute(s) ->
// cvt+ds_write(s+1) -> barrier. 4 independent blocks/CU hide each other's
// barrier drains (the round-6 killer was 2 blocks/CU).
// LDS tiles: 64-B rows, quad-XOR swizzle ((idx>>1)&3) on write and read.
// MFMA frag mapping (verified rounds 2-8): A lane=A[m][kg*8+j]; B lane=B[kg*8+j][m];
// D: col=m, row=kg*4+reg.
__global__ __launch_bounds__(256, 4) void cos_loss_k(
    const float* __restrict__ feats,
    const short* __restrict__ cnb2,
    const int* __restrict__ labels,
    const int* __restrict__ labelled,
    float* __restrict__ out) {
  const int tid = threadIdx.x;
  const int w = tid >> 6;            // wave id = column group (64 cols)
  const int lane = tid & 63;
  const int m = lane & 15;
  const int kg = lane >> 4;
  const int swzf = (m >> 1) & 3;     // frag-read quad swizzle
  const int rowBase = blockIdx.x * ROWSB;

  __shared__ short As[2][ROWSB][32];   // 4 KB
  __shared__ short Bs[2][CPAD][32];    // 32 KB
  __shared__ float invs[ROWSB];
  __shared__ int   labLds[ROWSB];
  __shared__ int   lblLds[ROWSB];
  __shared__ float l1part[4][ROWSB];
  __shared__ float alpart[4][ROWSB];
  // total ~38.4 KB -> 4 blocks/CU

  if (tid < ROWSB) {
    labLds[tid] = labels[rowBase + tid];
    lblLds[tid] = labelled[rowBase + tid];
  }

  // staging assignments
  // A: 8 thr/row; thread covers 4 floats (half-quad) of the 32-k step slice
  const int arow = tid >> 3;            // 0..31
  const int ac   = tid & 7;             // 0..7: quad aq=ac>>1, half ah=ac&1
  const int aq   = ac >> 1;
  const int ah   = ac & 1;
  const int aswz = (arow >> 1) & 3;
  const float* asrc = feats + (size_t)(rowBase + arow) * DIMS + ac * 4;
  short* adst0 = &As[0][arow][(aq ^ aswz) * 8 + ah * 4];
  short* adst1 = &As[1][arow][(aq ^ aswz) * 8 + ah * 4];
  // B: thread -> col tid, copies all 32 k (64 B contiguous in cnb2) as 4 quads
  const int bcol = tid;
  const int bswz = (bcol >> 1) & 3;
  const short* bsrc = cnb2 + bcol * KSTEP;

  f32x4 acc[2][4];
#pragma unroll
  for (int mi = 0; mi < 2; ++mi)
#pragma unroll
    for (int ni = 0; ni < 4; ++ni) acc[mi][ni] = (f32x4){0.f, 0.f, 0.f, 0.f};

  float ssq = 0.f;
  float4 pva;
  short8 pb0, pb1, pb2, pb3;

#define LOAD_STEP(step) do {                                             \
    pva = *(const float4*)(asrc + (step) * KSTEP);                       \
    const short* bp_ = bsrc + (size_t)(step) * (CPAD * KSTEP);           \
    pb0 = *(const short8*)(bp_ + 0);                                     \
    pb1 = *(const short8*)(bp_ + 8);                                     \
    pb2 = *(const short8*)(bp_ + 16);                                    \
    pb3 = *(const short8*)(bp_ + 24);                                    \
  } while (0)

#define WRITE_STEP(adst, buf) do {                                       \
    ssq += pva.x*pva.x + pva.y*pva.y + pva.z*pva.z + pva.w*pva.w;        \
    union { unsigned u[2]; } p_;                                         \
    p_.u[0] = pk_bf16(pva.x, pva.y);                                     \
    p_.u[1] = pk_bf16(pva.z, pva.w);                                     \
    *(unsigned*)(adst) = p_.u[0];                                        \
    *(unsigned*)((adst) + 2) = p_.u[1];                                  \
    *(short8*)(&Bs[(buf)][bcol][(0 ^ bswz) * 8]) = pb0;                  \
    *(short8*)(&Bs[(buf)][bcol][(1 ^ bswz) * 8]) = pb1;                  \
    *(short8*)(&Bs[(buf)][bcol][(2 ^ bswz) * 8]) = pb2;                  \
    *(short8*)(&Bs[(buf)][bcol][(3 ^ bswz) * 8]) = pb3;                  \
  } while (0)

#define COMPUTE(buf) do {                                                \
    short8 af0, af1, bf[4];                                              \
    af0 = *(const short8*)(&As[(buf)][m][(kg ^ swzf) * 8]);              \
    af1 = *(const short8*)(&As[(buf)][16 + m][(kg ^ swzf) * 8]);         \
    _Pragma("unroll")                                                    \
    for (int ni = 0; ni < 4; ++ni)                                       \
      bf[ni] = *(const short8*)(&Bs[(buf)][w * 64 + ni * 16 + m][(kg ^ swzf) * 8]); \
    _Pragma("unroll")                                                    \
    for (int ni = 0; ni < 4; ++ni) {                                     \
      acc[0][ni] = __builtin_amdgcn_mfma_f32_16x16x32_bf16(af0, bf[ni], acc[0][ni], 0, 0, 0); \
      acc[1][ni] = __builtin_amdgcn_mfma_f32_16x16x32_bf16(af1, bf[ni], acc[1][ni], 0, 0, 0); \
    }                                                                    \
  } while (0)

  // prologue: stage step 0 into buffer 0
  LOAD_STEP(0);
  WRITE_STEP(adst0, 0);
  __syncthreads();

  for (int ks = 0; ks < NSTEP; ks += 2) {
    // even phase: compute buf0, stage ks+1 -> buf1
    if (ks + 1 < NSTEP) LOAD_STEP(ks + 1);
    COMPUTE(0);
    if (ks + 1 < NSTEP) WRITE_STEP(adst1, 1);
    __syncthreads();
    // odd phase: compute buf1, stage ks+2 -> buf0
    if (ks + 1 < NSTEP) {
      if (ks + 2 < NSTEP) LOAD_STEP(ks + 2);
      COMPUTE(1);
      if (ks + 2 < NSTEP) WRITE_STEP(adst0, 0);
      __syncthreads();
    }
  }

#undef LOAD_STEP
#undef WRITE_STEP
#undef COMPUTE

  // ---- row inverse norms (fp32): reduce over the 8 staging threads of a row ----
  ssq += __shfl_xor(ssq, 1);
  ssq += __shfl_xor(ssq, 2);
  ssq += __shfl_xor(ssq, 4);
  if (ac == 0) invs[arow] = 1.f / fmaxf(sqrtf(ssq), 1e-8f);
  __syncthreads();

  // ---- epilogue: per-row l1 and label-|cos| ----
#pragma unroll
  for (int mi = 0; mi < 2; ++mi) {
    float l1r[4] = {0.f, 0.f, 0.f, 0.f};
    float alr[4] = {0.f, 0.f, 0.f, 0.f};
    float iv[4];
    int labr[4];
#pragma unroll
    for (int r = 0; r < 4; ++r) {
      const int row = mi * 16 + kg * 4 + r;
      iv[r] = invs[row];
      labr[r] = labLds[row];
    }
#pragma unroll
    for (int ni = 0; ni < 4; ++ni) {
      const int col = w * 64 + ni * 16 + m;
#pragma unroll
      for (int r = 0; r < 4; ++r) {
        const float a = fabsf(acc[mi][ni][r] * iv[r]);
        l1r[r] += a;
        if (col == labr[r]) alr[r] += a;
      }
    }
#pragma unroll
    for (int r = 0; r < 4; ++r) {
#pragma unroll
      for (int off = 1; off < 16; off <<= 1) {
        l1r[r] += __shfl_xor(l1r[r], off);
        alr[r] += __shfl_xor(alr[r], off);
      }
    }
    if (m == 0) {
#pragma unroll
      for (int r = 0; r < 4; ++r) {
        l1part[w][mi * 16 + kg * 4 + r] = l1r[r];
        alpart[w][mi * 16 + kg * 4 + r] = alr[r];
      }
    }
  }
  __syncthreads();

  if (tid < ROWSB) {
    const float L = l1part[0][tid] + l1part[1][tid] + l1part[2][tid] + l1part[3][tid];
    const float A = alpart[0][tid] + alpart[1][tid] + alpart[2][tid] + alpart[3][tid];
    float c = lblLds[tid] ? (L - 2.f * A) / fmaxf(L, 1e-12f) : 0.f;
#pragma unroll
    for (int off = 1; off < 32; off <<= 1) c += __shfl_xor(c, off);
    if (tid == 0) atomicAdd(out, c);
  }
}

extern "C" void kernel_launch(void* const* d_in, const int* in_sizes, int n_in,
                              void* d_out, int out_size, void* d_ws, size_t ws_size,
                              hipStream_t stream) {
  const float* feats = (const float*)d_in[0];
  const float* centers = (const float*)d_in[1];
  const int* labels = (const int*)d_in[2];
  const int* labelled = (const int*)d_in[3];
  float* out = (float*)d_out;
  short* cnb2 = (short*)d_ws;  // [24][256][32] bf16 = 393216 B

  prep_centers_k<<<CPAD, 256, 0, stream>>>(centers, cnb2, out);
  cos_loss_k<<<NROWS / ROWSB, 256, 0, stream>>>(feats, cnb2, labels, labelled, out);
}

// Round 10
// 38.409 us; speedup vs baseline: 1.3149x; 1.3149x over previous
//
#include <hip/hip_runtime.h>
#include <hip/hip_bf16.h>

// Problem constants: B=32768, D=768, C=200.
#define NROWS 32768
#define DIMS  768
#define NC    200
#define CPAD  256
#define KSTEP 32
#define NSTEP (DIMS / KSTEP)   // 24
#define ROWSB 64               // M-tile rows per block -> grid 512

typedef __attribute__((ext_vector_type(8))) short short8;   // 8 bf16
typedef __attribute__((ext_vector_type(4))) float f32x4;

__device__ __forceinline__ unsigned pk_bf16(float lo, float hi) {
  union { __hip_bfloat162 h; unsigned u; } c;
  c.h = __float22bfloat162_rn(make_float2(lo, hi));
  return c.u;
}

// async global->LDS DMA, 16 B per lane, LDS dest = wave-uniform base + lane*16
__device__ __forceinline__ void glds16(const void* g, void* l) {
  __builtin_amdgcn_global_load_lds(
      (const __attribute__((address_space(1))) unsigned int*)g,
      (__attribute__((address_space(3))) unsigned int*)l, 16, 0, 0);
}

// Kernel 1: L2-normalize centers -> bf16, K-blocked layout WITH the quad
// swizzle pre-baked (m173 pattern): logical (c,d): ks=d>>5, q=(d&31)>>3,
// j=d&7 stored at phys idx = ks*CPAD*32 + c*32 + (q ^ ((c>>1)&3))*8 + j.
// A linear 1 KB DMA chunk then lands swizzled in LDS. Rows >= NC zero.
__global__ __launch_bounds__(256) void prep_centers_k(const float* __restrict__ centers,
                                                      short* __restrict__ cnb2,
                                                      float* __restrict__ out) {
  const int c = blockIdx.x;
  const int tid = threadIdx.x;
  if (c == 0 && tid == 0) out[0] = 0.f;
  const int cswz = (c >> 1) & 3;
  if (c >= NC) {
    for (int d = tid; d < DIMS; d += 256)
      cnb2[(d >> 5) * (CPAD * KSTEP) + c * KSTEP + d % 32] = 0;
    return;
  }
  float ssq = 0.f;
  for (int d = tid; d < DIMS; d += 256) {
    float v = centers[c * DIMS + d];
    ssq += v * v;
  }
#pragma unroll
  for (int off = 32; off > 0; off >>= 1) ssq += __shfl_down(ssq, off);
  __shared__ float red[4];
  const int wid = tid >> 6, lane = tid & 63;
  if (lane == 0) red[wid] = ssq;
  __syncthreads();
  const float tot = red[0] + red[1] + red[2] + red[3];
  const float inv = 1.f / fmaxf(sqrtf(tot), 1e-8f);
  for (int d = tid; d < DIMS; d += 256) {
    const float v = centers[c * DIMS + d] * inv;
    union { __hip_bfloat16 h; short s; } cv;
    cv.h = __float2bfloat16(v);
    const int ks = d >> 5, dk = d & 31, q = dk >> 3, j = dk & 7;
    cnb2[ks * (CPAD * KSTEP) + c * KSTEP + ((q ^ cswz) * 8 + j)] = cv.s;
  }
}

// Kernel 2: round-6 dbuf structure, m97-ified.
//  - B staged by global_load_lds DMA (wave-private: wave w DMAs+reads its own
//    64 cols). 4 DMA instrs/wave/step, no VGPRs, no staging VALU.
//  - A reg-staged (fp32 load + pk_bf16 cvt + ssq) with depth-2 named slots.
//  - LDS rows 64 B, quad-XOR swizzle (q ^ ((row>>1)&3)); frag reads <=2-way.
// MFMA frag mapping (verified rounds 2-9): A lane=A[m][kg*8+j];
// B lane=B[kg*8+j][m]; D: col=m, row=kg*4+reg.
__global__ __launch_bounds__(256) void cos_loss_k(
    const float* __restrict__ feats,
    const short* __restrict__ cnb2,
    const int* __restrict__ labels,
    const int* __restrict__ labelled,
    float* __restrict__ out) {
  const int tid = threadIdx.x;
  const int w = tid >> 6;            // wave id = column group (64 cols)
  const int lane = tid & 63;
  const int m = lane & 15;
  const int kg = lane >> 4;
  const int sq = (kg ^ ((m >> 1) & 3)) * 8;   // frag quad offset (A and B)
  const int rowBase = blockIdx.x * ROWSB;

  __shared__ short As[2][ROWSB][32];   // 8 KB
  __shared__ short Bs[2][CPAD][32];    // 32 KB
  __shared__ float invs[ROWSB];
  __shared__ int   labLds[ROWSB];
  __shared__ int   lblLds[ROWSB];
  __shared__ float l1part[4][ROWSB];
  __shared__ float alpart[4][ROWSB];
  // ~43 KB -> 3 blocks/CU by LDS (grid gives 2)

  if (tid < ROWSB) {
    labLds[tid] = labels[rowBase + tid];
    lblLds[tid] = labelled[rowBase + tid];
  }

  // A staging: 4 thr/row, thread covers 8 floats (one quad) of the 32-k slice
  const int arow = tid >> 2;            // 0..63
  const int aq   = tid & 3;
  const int aswz = (arow >> 1) & 3;
  const float* asrc = feats + (size_t)(rowBase + arow) * DIMS + aq * 8;
  short* adst[2] = { &As[0][arow][(aq ^ aswz) * 8], &As[1][arow][(aq ^ aswz) * 8] };
  // B DMA: wave w stages its own cols w*64..w*64+63 = 4 chunks of 1 KB
  const short* bbase = cnb2 + (size_t)(w * 64) * KSTEP + lane * 8;

  f32x4 acc[4][4];
#pragma unroll
  for (int mi = 0; mi < 4; ++mi)
#pragma unroll
    for (int ni = 0; ni < 4; ++ni) acc[mi][ni] = (f32x4){0.f, 0.f, 0.f, 0.f};

  float ssq = 0.f;
  float4 S0_lo, S0_hi, S1_lo, S1_hi;   // depth-2 A slots (static names)

#define LOADA(P, step) do {                                              \
    const float* ap_ = asrc + (step) * KSTEP;                            \
    P##_lo = *(const float4*)(ap_);                                      \
    P##_hi = *(const float4*)(ap_ + 4);                                  \
  } while (0)

#define WRITEA(P, buf) do {                                              \
    ssq += P##_lo.x*P##_lo.x + P##_lo.y*P##_lo.y                         \
         + P##_lo.z*P##_lo.z + P##_lo.w*P##_lo.w;                        \
    ssq += P##_hi.x*P##_hi.x + P##_hi.y*P##_hi.y                         \
         + P##_hi.z*P##_hi.z + P##_hi.w*P##_hi.w;                        \
    union { short8 s; unsigned u[4]; } p_;                               \
    p_.u[0] = pk_bf16(P##_lo.x, P##_lo.y);                               \
    p_.u[1] = pk_bf16(P##_lo.z, P##_lo.w);                               \
    p_.u[2] = pk_bf16(P##_hi.x, P##_hi.y);                               \
    p_.u[3] = pk_bf16(P##_hi.z, P##_hi.w);                               \
    *(short8*)(adst[(buf)]) = p_.s;                                      \
  } while (0)

#define DMAB(step, buf) do {                                             \
    const short* g_ = bbase + (size_t)(step) * (CPAD * KSTEP);           \
    glds16(g_ + 0 * (16 * KSTEP), &Bs[(buf)][w * 64 + 0 * 16][0]);       \
    glds16(g_ + 1 * (16 * KSTEP), &Bs[(buf)][w * 64 + 1 * 16][0]);       \
    glds16(g_ + 2 * (16 * KSTEP), &Bs[(buf)][w * 64 + 2 * 16][0]);       \
    glds16(g_ + 3 * (16 * KSTEP), &Bs[(buf)][w * 64 + 3 * 16][0]);       \
  } while (0)

#define COMPUTE(buf) do {                                                \
    short8 af[4], bf[4];                                                 \
    _Pragma("unroll")                                                    \
    for (int mi = 0; mi < 4; ++mi)                                       \
      af[mi] = *(const short8*)(&As[(buf)][mi * 16 + m][sq]);            \
    _Pragma("unroll")                                                    \
    for (int ni = 0; ni < 4; ++ni)                                       \
      bf[ni] = *(const short8*)(&Bs[(buf)][w * 64 + ni * 16 + m][sq]);   \
    _Pragma("unroll")                                                    \
    for (int mi = 0; mi < 4; ++mi)                                       \
      _Pragma("unroll")                                                  \
      for (int ni = 0; ni < 4; ++ni)                                     \
        acc[mi][ni] = __builtin_amdgcn_mfma_f32_16x16x32_bf16(           \
            af[mi], bf[ni], acc[mi][ni], 0, 0, 0);                       \
  } while (0)

  // prologue
  LOADA(S0, 0);
  LOADA(S1, 1);
  DMAB(0, 0);
  WRITEA(S0, 0);
  __syncthreads();   // drains DMA(step0) + A writes

  for (int ks = 0; ks < NSTEP; ks += 2) {
    // even phase: compute buf0 (step ks)
    DMAB(ks + 1, 1);
    if (ks + 2 < NSTEP) LOADA(S0, ks + 2);
    WRITEA(S1, 1);
    COMPUTE(0);
    __syncthreads();
    // odd phase: compute buf1 (step ks+1)
    if (ks + 2 < NSTEP) {
      DMAB(ks + 2, 0);
      if (ks + 3 < NSTEP) LOADA(S1, ks + 3);
      WRITEA(S0, 0);
    }
    COMPUTE(1);
    __syncthreads();
  }

#undef LOADA
#undef WRITEA
#undef DMAB
#undef COMPUTE

  // ---- row inverse norms (fp32): reduce over the 4 staging threads of a row ----
  ssq += __shfl_xor(ssq, 1);
  ssq += __shfl_xor(ssq, 2);
  if ((tid & 3) == 0) invs[arow] = 1.f / fmaxf(sqrtf(ssq), 1e-8f);
  __syncthreads();

  // ---- epilogue: per-row l1 and label-|cos| ----
#pragma unroll
  for (int mi = 0; mi < 4; ++mi) {
    float l1r[4] = {0.f, 0.f, 0.f, 0.f};
    float alr[4] = {0.f, 0.f, 0.f, 0.f};
    float iv[4];
    int labr[4];
#pragma unroll
    for (int r = 0; r < 4; ++r) {
      const int row = mi * 16 + kg * 4 + r;
      iv[r] = invs[row];
      labr[r] = labLds[row];
    }
#pragma unroll
    for (int ni = 0; ni < 4; ++ni) {
      const int col = w * 64 + ni * 16 + m;
#pragma unroll
      for (int r = 0; r < 4; ++r) {
        const float a = fabsf(acc[mi][ni][r] * iv[r]);
        l1r[r] += a;
        if (col == labr[r]) alr[r] += a;
      }
    }
#pragma unroll
    for (int r = 0; r < 4; ++r) {
#pragma unroll
      for (int off = 1; off < 16; off <<= 1) {
        l1r[r] += __shfl_xor(l1r[r], off);
        alr[r] += __shfl_xor(alr[r], off);
      }
    }
    if (m == 0) {
#pragma unroll
      for (int r = 0; r < 4; ++r) {
        l1part[w][mi * 16 + kg * 4 + r] = l1r[r];
        alpart[w][mi * 16 + kg * 4 + r] = alr[r];
      }
    }
  }
  __syncthreads();

  if (tid < ROWSB) {
    const float L = l1part[0][tid] + l1part[1][tid] + l1part[2][tid] + l1part[3][tid];
    const float A = alpart[0][tid] + alpart[1][tid] + alpart[2][tid] + alpart[3][tid];
    float c = lblLds[tid] ? (L - 2.f * A) / fmaxf(L, 1e-12f) : 0.f;
#pragma unroll
    for (int off = 1; off < 64; off <<= 1) c += __shfl_xor(c, off);
    if (tid == 0) atomicAdd(out, c);
  }
}

extern "C" void kernel_launch(void* const* d_in, const int* in_sizes, int n_in,
                              void* d_out, int out_size, void* d_ws, size_t ws_size,
                              hipStream_t stream) {
  const float* feats = (const float*)d_in[0];
  const float* centers = (const float*)d_in[1];
  const int* labels = (const int*)d_in[2];
  const int* labelled = (const int*)d_in[3];
  float* out = (float*)d_out;
  short* cnb2 = (short*)d_ws;  // [24][256][32] bf16, quad-swizzle baked in

  prep_centers_k<<<CPAD, 256, 0, stream>>>(centers, cnb2, out);
  cos_loss_k<<<NROWS / ROWSB, 256, 0, stream>>>(feats, cnb2, labels, labelled, out);
}